// Round 7
// baseline (339.587 us; speedup 1.0000x reference)
//
#include <hip/hip_runtime.h>
#include <stdint.h>

// ---------------------------------------------------------------------------
// StageBranchRunnerN2 round 11:
//  - r10 post-mortem: gfuse_router is now the top dispatch (56 us, MfmaUtil
//    10%, HBM 6%, Occ 20.5%) -- latency-bound at 512 blocks = 2/CU, the same
//    disease gexp1 had in r4. Apply the r5-proven fix (occupancy, not
//    schedule): re-tile router+bank fused GEMMs to 32x64 tiles -> 1024
//    blocks = 4/CU = 4 waves/SIMD. Waves 2x2 of 16x32 (acc[2]); A staged by
//    threads 0-127 (2 KB/buf), B by all 256; swizzle identity re-verified
//    for 32-row tiles; LDS 24/34 KB.
//  - everything else unchanged from r10.
// ---------------------------------------------------------------------------

typedef unsigned short u16;
using bf16x8 = __attribute__((ext_vector_type(8))) short;
using f32x4  = __attribute__((ext_vector_type(4))) float;

// ws layout (ws >= 75,497,472 B)
#define WS_HHI 0u
#define WS_HLO 16777216u
#define WS_PB2 33554432u
#define WS_W1T 67108864u
#define WS_IDX 71303168u
// idx sub-offsets (bytes from ws+WS_IDX)
#define IX_SELE   0u        // int[16384]
#define IX_SELG   65536u    // float[16384]
#define IX_ROW    131072u   // int[16384]
#define IX_TOKR   196608u   // int[16384]
#define IX_GROW   262144u   // float[16384]
#define IX_CNT    327680u   // int[256*8]
#define IX_CBASE  335872u   // int[256*8]
#define IX_TILEE  344064u   // int[160]
#define IX_TILES  344704u   // int[160]
#define IX_TILEC  345344u   // int[160]
#define IX_META   345984u   // int[32]: [16]=nTiles128 [17]=nTiles64
#define IX_TILEE2 346112u   // int[288]
#define IX_TILES2 347264u   // int[288]
#define IX_TILEC2 348416u   // int[288]
#define IX_PLOG   1048576u  // float[8192][32] = 1 MB

__device__ __forceinline__ float gelu_tanh(float x) {
  float x3 = x * x * x;
  float t = tanhf(0.7978845608028654f * (x + 0.044715f * x3));
  return 0.5f * x * (1.0f + t);
}
__device__ __forceinline__ u16 f2bf(float f) {
  uint32_t u = __float_as_uint(f);
  u = u + 0x7fffu + ((u >> 16) & 1u);
  return (u16)(u >> 16);
}
__device__ __forceinline__ float b2f(u16 h) {
  return __uint_as_float(((uint32_t)h) << 16);
}
__device__ __forceinline__ void gll16(const void* g, void* l) {
  __builtin_amdgcn_global_load_lds(
      (const __attribute__((address_space(1))) void*)g,
      (__attribute__((address_space(3))) void*)l, 16, 0, 0);
}

// ---------------------------------------------------------------------------
// LDS-tiled transpose + bf16 split: in f32 [z][inR][inC] -> out bf16
// out[(z*inC + c)*outLD + outColOff + r]. 64x64 tile, coalesced both sides.
// ---------------------------------------------------------------------------
__global__ __launch_bounds__(256) void tsplit_kernel(const float* __restrict__ in,
    int inR, int inC, u16* __restrict__ outHi, u16* __restrict__ outLo,
    int outLD, int outColOff) {
  __shared__ u16 hs[64][65];
  __shared__ u16 ls[64][65];
  int tid = threadIdx.x;
  int c0 = blockIdx.x * 64, r0 = blockIdx.y * 64;
  const float* inp = in + (size_t)blockIdx.z * inR * inC;
  int rl = tid >> 6, cl = tid & 63;
#pragma unroll
  for (int p = 0; p < 16; p++) {
    int r = rl + p * 4;
    float v = inp[(size_t)(r0 + r) * inC + c0 + cl];
    u16 h = f2bf(v);
    hs[r][cl] = h;
    ls[r][cl] = f2bf(v - b2f(h));
  }
  __syncthreads();
  size_t obase = (size_t)(blockIdx.z * inC + c0) * outLD + outColOff + r0;
#pragma unroll
  for (int p = 0; p < 16; p++) {
    int c = rl + p * 4;
    outHi[obase + (size_t)c * outLD + cl] = hs[cl][c];
    if (outLo) outLo[obase + (size_t)c * outLD + cl] = ls[cl][c];
  }
}

// ---------------------------------------------------------------------------
// W' = fp_w2 @ r_w1[1024:1280,:], b' = r_b1 + fp_b2 @ r_w1[1024:]
// ---------------------------------------------------------------------------
__global__ __launch_bounds__(256) void wprime_kernel(const float* __restrict__ fp_w2,
    const float* __restrict__ r_w1, const float* __restrict__ fp_b2,
    const float* __restrict__ r_b1, float* __restrict__ wp, float* __restrict__ bp) {
  __shared__ float row[256];
  int i = blockIdx.x, n = threadIdx.x;
  if (i < 256) {
    row[n] = fp_w2[i * 256 + n];
    __syncthreads();
    float acc = 0.0f;
    for (int j = 0; j < 256; j++) acc += row[j] * r_w1[(size_t)(1024 + j) * 256 + n];
    wp[i * 256 + n] = acc;
  } else {
    row[n] = fp_b2[n];
    __syncthreads();
    float acc = r_b1[n];
    for (int j = 0; j < 256; j++) acc += row[j] * r_w1[(size_t)(1024 + j) * 256 + n];
    bp[n] = acc;
  }
}

// ---------------------------------------------------------------------------
// LayerNorm -> h hi/lo bf16 split; rule logits.
// ---------------------------------------------------------------------------
__global__ __launch_bounds__(256) void ln_kernel(const float* __restrict__ hidden,
    const float* __restrict__ ln_g, const float* __restrict__ ln_b,
    const float* __restrict__ feat, const float* __restrict__ rr_w,
    const float* __restrict__ rr_b,
    u16* __restrict__ h_hi, u16* __restrict__ h_lo, float* __restrict__ rule) {
  int t = blockIdx.x;
  int tid = threadIdx.x;
  float4 v = ((const float4*)(hidden + (size_t)t * 1024))[tid];
  float s = v.x + v.y + v.z + v.w;
#pragma unroll
  for (int o = 32; o > 0; o >>= 1) s += __shfl_down(s, o);
  __shared__ float red[4];
  __shared__ float stats[2];
  int wid = tid >> 6, lane = tid & 63;
  if (lane == 0) red[wid] = s;
  __syncthreads();
  if (tid == 0) stats[0] = (red[0] + red[1] + red[2] + red[3]) * (1.0f / 1024.0f);
  __syncthreads();
  float mu = stats[0];
  float dx = v.x - mu, dy = v.y - mu, dz = v.z - mu, dw = v.w - mu;
  float q = dx * dx + dy * dy + dz * dz + dw * dw;
#pragma unroll
  for (int o = 32; o > 0; o >>= 1) q += __shfl_down(q, o);
  if (lane == 0) red[wid] = q;
  __syncthreads();
  if (tid == 0) {
    float var = (red[0] + red[1] + red[2] + red[3]) * (1.0f / 1024.0f) + 1e-5f;
    float r = rsqrtf(var);
    r = r * (1.5f - 0.5f * var * r * r);
    stats[1] = r;
  }
  __syncthreads();
  float r = stats[1];
  float4 g = ((const float4*)ln_g)[tid];
  float4 b = ((const float4*)ln_b)[tid];
  float4 o;
  o.x = dx * r * g.x + b.x;
  o.y = dy * r * g.y + b.y;
  o.z = dz * r * g.z + b.z;
  o.w = dw * r * g.w + b.w;
  ushort4 hv, lv;
  hv.x = f2bf(o.x); lv.x = f2bf(o.x - b2f(hv.x));
  hv.y = f2bf(o.y); lv.y = f2bf(o.y - b2f(hv.y));
  hv.z = f2bf(o.z); lv.z = f2bf(o.z - b2f(hv.z));
  hv.w = f2bf(o.w); lv.w = f2bf(o.w - b2f(hv.w));
  ((ushort4*)(h_hi + (size_t)t * 1024))[tid] = hv;
  ((ushort4*)(h_lo + (size_t)t * 1024))[tid] = lv;
  if (tid < 8) {
    float acc = rr_b[tid];
#pragma unroll
    for (int f = 0; f < 16; f++) acc += feat[t * 16 + f] * rr_w[f * 8 + tid];
    rule[t * 8 + tid] = acc;
  }
}

// ---------------------------------------------------------------------------
// 32x64-tile fused GEMM compute: wave (wr in {0,16}, wc in {0,32}) owns a
// 16x32 sub-tile = 1 A-frag x 2 B-frags; 3-product split-bf16; 6 MFMA.
// ---------------------------------------------------------------------------
#define GF32_COMPUTE(AH, AL, BH, BL)                                           \
  {                                                                            \
    bf16x8 ah = *((const bf16x8*)(AH + (wr + l16) * 32 + xq * 8));             \
    bf16x8 al = *((const bf16x8*)(AL + (wr + l16) * 32 + xq * 8));             \
    _Pragma("unroll") for (int j = 0; j < 2; j++) {                            \
      bf16x8 bh = *((const bf16x8*)(BH + (wc + j * 16 + l16) * 32 + xq * 8));  \
      bf16x8 bl = *((const bf16x8*)(BL + (wc + j * 16 + l16) * 32 + xq * 8));  \
      acc[j] = __builtin_amdgcn_mfma_f32_16x16x32_bf16(ah, bh, acc[j], 0, 0, 0); \
      acc[j] = __builtin_amdgcn_mfma_f32_16x16x32_bf16(al, bh, acc[j], 0, 0, 0); \
      acc[j] = __builtin_amdgcn_mfma_f32_16x16x32_bf16(ah, bl, acc[j], 0, 0, 0); \
    }                                                                          \
  }

// ---------------------------------------------------------------------------
// proj1 FUSED + bank-split FUSED: mid = gelu(feat_bank @ fp_w1 + fp_b1).
// 32x64 tiles, 1024 blocks XCD-grouped. A reg-staged from f32 by threads
// 0-127 (float4 -> hi/lo bf16 -> swizzled ds_write); B via gll16.
// ---------------------------------------------------------------------------
__global__ __launch_bounds__(256) void gfuse_bank_kernel(
    const float* __restrict__ Af,            // [8192][512] f32
    const u16* __restrict__ Bth, const u16* __restrict__ Btl,  // [256][512]
    const float* __restrict__ bias,
    u16* __restrict__ outHi, u16* __restrict__ outLo) {
  __shared__ u16 Ash0[1024], Ash1[1024];
  __shared__ u16 Asl0[1024], Asl1[1024];
  __shared__ u16 Bsh0[2048], Bsh1[2048];
  __shared__ u16 Bsl0[2048], Bsl1[2048];
  int tid = threadIdx.x;
  int n = blockIdx.x;
  int rowt = ((n >> 5) << 3) + (n & 7);     // 0..255
  int cblk = (n >> 3) & 3;
  int row0 = rowt * 32, col0 = cblk * 64;
  int wave = tid >> 6, lane = tid & 63;
  int wr = (wave >> 1) * 16, wc = (wave & 1) * 32;
  int l16 = lane & 15, qd = lane >> 4;
  int xq = qd ^ ((l16 >> 1) & 3);
  f32x4 acc[2];
  acc[0] = 0.0f; acc[1] = 0.0f;

  int r0 = tid >> 2, kc = tid & 3;
  int ra = r0 & 31;                          // A row (threads 0-127)
  int kas8 = (kc ^ ((ra >> 1) & 3)) * 8;     // A swizzled k-slot (halves)
  int kbs8 = (kc ^ ((r0 >> 1) & 3)) * 8;     // B swizzled k-slot
  const float* Ap = Af + (size_t)(row0 + ra) * 512 + kc * 8;   // logical slot
  const u16* Bhp = Bth + (size_t)(col0 + r0) * 512 + kbs8;     // pre-swizzled
  const u16* Blp = Btl + (size_t)(col0 + r0) * 512 + kbs8;
  int aw = ra * 32 + kas8;                   // swizzled LDS write offset

  union U8 { ushort u[8]; bf16x8 v; };

#define GFB_STAGE(K, AH, AL, BH, BL)                                  \
  {                                                                   \
    gll16(Bhp + (K), BH + tid * 8);                                   \
    gll16(Blp + (K), BL + tid * 8);                                   \
    if (tid < 128) {                                                  \
      float4 va = *(const float4*)(Ap + (K));                         \
      float4 vb = *(const float4*)(Ap + (K) + 4);                     \
      float fv[8] = {va.x, va.y, va.z, va.w, vb.x, vb.y, vb.z, vb.w}; \
      U8 H, L;                                                        \
      _Pragma("unroll") for (int q = 0; q < 8; q++) {                 \
        H.u[q] = f2bf(fv[q]);                                         \
        L.u[q] = f2bf(fv[q] - b2f(H.u[q]));                           \
      }                                                               \
      *(bf16x8*)(AH + aw) = H.v;                                      \
      *(bf16x8*)(AL + aw) = L.v;                                      \
    }                                                                 \
  }

  GFB_STAGE(0, Ash0, Asl0, Bsh0, Bsl0);
  __syncthreads();
  for (int k0 = 0; k0 < 512; k0 += 64) {
    GFB_STAGE(k0 + 32, Ash1, Asl1, Bsh1, Bsl1);
    GF32_COMPUTE(Ash0, Asl0, Bsh0, Bsl0);
    __syncthreads();
    if (k0 + 64 < 512) {
      GFB_STAGE(k0 + 64, Ash0, Asl0, Bsh0, Bsl0);
    }
    GF32_COMPUTE(Ash1, Asl1, Bsh1, Bsl1);
    __syncthreads();
  }
#undef GFB_STAGE

#pragma unroll
  for (int j = 0; j < 2; j++) {
    int cl = wc + j * 16 + l16;
    float bc = bias[col0 + cl];
#pragma unroll
    for (int rr = 0; rr < 4; rr++) {
      int rl = wr + qd * 4 + rr;
      float v = gelu_tanh(acc[j][rr] + bc);
      u16 h = f2bf(v);
      size_t o = (size_t)(row0 + rl) * 256 + col0 + cl;
      outHi[o] = h;
      outLo[o] = f2bf(v - b2f(h));
    }
  }
}

// ---------------------------------------------------------------------------
// router FUSED, r1 never materialized: 32x64 tiles, 1024 blocks. Per-block
// r1 tile (32x64) contracted with r_w2[col0:+64, 0:8] -> plog partials.
// K = 1024 (h hi/lo) + 256 (mid hi/lo). A staged by threads 0-127.
// ---------------------------------------------------------------------------
__global__ __launch_bounds__(256) void gfuse_router_kernel(
    const u16* __restrict__ A1h, const u16* __restrict__ A1l,   // [8192][1024]
    const u16* __restrict__ A2h, const u16* __restrict__ A2l,   // [8192][256]
    const u16* __restrict__ Bth, const u16* __restrict__ Btl,   // [256][1280]
    const float* __restrict__ bias, const float* __restrict__ r_w2,
    float* __restrict__ plog) {
  __shared__ u16 Ash0[1024], Ash1[1024];
  __shared__ u16 Asl0[1024], Asl1[1024];
  __shared__ u16 Bsh0[2048], Bsh1[2048];
  __shared__ u16 Bsl0[2048], Bsl1[2048];
  __shared__ float r1s[32][65];
  __shared__ float w2s[64][8];
  int tid = threadIdx.x;
  int n = blockIdx.x;
  int rowt = ((n >> 5) << 3) + (n & 7);
  int cblk = (n >> 3) & 3;
  int row0 = rowt * 32, col0 = cblk * 64;
  int wave = tid >> 6, lane = tid & 63;
  int wr = (wave >> 1) * 16, wc = (wave & 1) * 32;
  int l16 = lane & 15, qd = lane >> 4;
  int xq = qd ^ ((l16 >> 1) & 3);
  f32x4 acc[2];
  acc[0] = 0.0f; acc[1] = 0.0f;

  int r0 = tid >> 2, kc = tid & 3;
  int ra = r0 & 31;
  int kas8 = (kc ^ ((ra >> 1) & 3)) * 8;
  int kbs8 = (kc ^ ((r0 >> 1) & 3)) * 8;
  const u16* A1hp = A1h + (size_t)(row0 + ra) * 1024 + kas8;
  const u16* A1lp = A1l + (size_t)(row0 + ra) * 1024 + kas8;
  const u16* A2hp = A2h + (size_t)(row0 + ra) * 256 + kas8;
  const u16* A2lp = A2l + (size_t)(row0 + ra) * 256 + kas8;
  const u16* Bhp = Bth + (size_t)(col0 + r0) * 1280 + kbs8;
  const u16* Blp = Btl + (size_t)(col0 + r0) * 1280 + kbs8;

#define GFR_STAGE(K, AH, AL, BH, BL)                      \
  {                                                       \
    int kk = (K);                                         \
    gll16(Bhp + kk, BH + tid * 8);                        \
    gll16(Blp + kk, BL + tid * 8);                        \
    if (tid < 128) {                                      \
      if (kk < 1024) {                                    \
        gll16(A1hp + kk, AH + tid * 8);                   \
        gll16(A1lp + kk, AL + tid * 8);                   \
      } else {                                            \
        gll16(A2hp + (kk - 1024), AH + tid * 8);          \
        gll16(A2lp + (kk - 1024), AL + tid * 8);          \
      }                                                   \
    }                                                     \
  }

  GFR_STAGE(0, Ash0, Asl0, Bsh0, Bsl0);
  __syncthreads();
  for (int k0 = 0; k0 < 1280; k0 += 64) {
    GFR_STAGE(k0 + 32, Ash1, Asl1, Bsh1, Bsl1);
    GF32_COMPUTE(Ash0, Asl0, Bsh0, Bsl0);
    __syncthreads();
    if (k0 + 64 < 1280) {
      GFR_STAGE(k0 + 64, Ash0, Asl0, Bsh0, Bsl0);
    }
    GF32_COMPUTE(Ash1, Asl1, Bsh1, Bsl1);
    __syncthreads();
  }
#undef GFR_STAGE

  // epilogue: r1 tile -> LDS, contract with w2 slice -> partial logits
#pragma unroll
  for (int j = 0; j < 2; j++) {
    int cl = wc + j * 16 + l16;
    float bc = bias[col0 + cl];
#pragma unroll
    for (int rr = 0; rr < 4; rr++) {
      int rl = wr + qd * 4 + rr;
      r1s[rl][cl] = gelu_tanh(acc[j][rr] + bc);
    }
  }
  for (int i = tid; i < 512; i += 256)
    w2s[i >> 3][i & 7] = r_w2[(size_t)(col0 + (i >> 3)) * 8 + (i & 7)];
  __syncthreads();
  {
    int tok = tid >> 3, e = tid & 7;       // 256 threads = 32 tok x 8 experts
    float L = 0.0f;
#pragma unroll
    for (int c = 0; c < 64; c++) L += r1s[tok][c] * w2s[c][e];
    plog[(size_t)(row0 + tok) * 32 + cblk * 8 + e] = L;
  }
}

// ---------------------------------------------------------------------------
// Gate: logits from plog partials, top-2 softmax, outputs, per-chunk counts.
// ---------------------------------------------------------------------------
__global__ __launch_bounds__(256) void gate_kernel(const float* __restrict__ plog,
    const float* __restrict__ r_b2,
    float* __restrict__ gates, float* __restrict__ slog, float* __restrict__ gw,
    int* __restrict__ selE, float* __restrict__ selG, int* __restrict__ cnt) {
  __shared__ float lg[32][8];
  __shared__ int se_s[64];
  int tid = threadIdx.x;
  int blk = blockIdx.x;
  int t0 = blk * 32;
  {
    int tl = tid >> 3, e = tid & 7;
    const float* pp = plog + (size_t)(t0 + tl) * 32 + e;
    lg[tl][e] = r_b2[e] + pp[0] + pp[8] + pp[16] + pp[24];
  }
  __syncthreads();
  if (tid < 32) {
    int t = t0 + tid;
    float l[8];
#pragma unroll
    for (int i = 0; i < 8; i++) l[i] = lg[tid][i];
    float m1 = -1e30f, m2 = -1e30f;
    int i1 = 0, i2 = 0;
#pragma unroll
    for (int i = 0; i < 8; i++) {
      float v = l[i];
      if (v > m1) { m2 = m1; i2 = i1; m1 = v; i1 = i; }
      else if (v > m2) { m2 = v; i2 = i; }
    }
    float w[8];
    float se = 0.0f;
#pragma unroll
    for (int i = 0; i < 8; i++) {
      float ex = (l[i] >= m2) ? expf(l[i] - m1) : 0.0f;
      w[i] = ex;
      se += ex;
    }
    float inv = 1.0f / se;
#pragma unroll
    for (int i = 0; i < 8; i++) {
      gates[(size_t)t * 8 + i] = w[i] * inv;
      slog[(size_t)t * 8 + i] = l[i];
    }
#pragma unroll
    for (int gi = 0; gi < 4; gi++)
      gw[(size_t)t * 4 + gi] = (w[2 * gi] + w[2 * gi + 1]) * inv;
    se_s[tid * 2] = i1;
    se_s[tid * 2 + 1] = i2;
    selE[t * 2] = i1;      selG[t * 2] = w[i1] * inv;
    selE[t * 2 + 1] = i2;  selG[t * 2 + 1] = w[i2] * inv;
  }
  __syncthreads();
  if (tid < 8) {
    int c = 0;
#pragma unroll
    for (int s = 0; s < 64; s++) c += (se_s[s] == tid) ? 1 : 0;
    cnt[blk * 8 + tid] = c;
  }
}

// ---------------------------------------------------------------------------
// stageB: expert totals -> bases -> per-chunk bases; tile maps (128 and 64).
// ---------------------------------------------------------------------------
__global__ __launch_bounds__(256) void stageb_kernel(const int* __restrict__ cnt,
    int* __restrict__ cbase, int* __restrict__ tileE, int* __restrict__ tileS,
    int* __restrict__ tileC, int* __restrict__ tileE2, int* __restrict__ tileS2,
    int* __restrict__ tileC2, int* __restrict__ meta) {
  __shared__ int cs[2048];
  __shared__ int tot[8];
  __shared__ int ebase[8];
  int tid = threadIdx.x;
  for (int i = tid; i < 2048; i += 256) cs[i] = cnt[i];
  __syncthreads();
  if (tid < 8) {
    int s = 0;
    for (int c = 0; c < 256; c++) s += cs[c * 8 + tid];
    tot[tid] = s;
  }
  __syncthreads();
  if (tid == 0) {
    int b = 0, nt = 0;
    for (int e = 0; e < 8; e++) {
      ebase[e] = b;
      int c = tot[e];
      for (int off = 0; off < c; off += 128) {
        tileE[nt] = e; tileS[nt] = b + off;
        tileC[nt] = (c - off < 128) ? (c - off) : 128;
        nt++;
      }
      b += c;
    }
    meta[16] = nt;
    int b2 = 0, nt2 = 0;
    for (int e = 0; e < 8; e++) {
      int c = tot[e];
      for (int off = 0; off < c; off += 64) {
        tileE2[nt2] = e; tileS2[nt2] = b2 + off;
        tileC2[nt2] = (c - off < 64) ? (c - off) : 64;
        nt2++;
      }
      b2 += c;
    }
    meta[17] = nt2;
  }
  __syncthreads();
  if (tid < 8) {
    int run = ebase[tid];
    for (int c = 0; c < 256; c++) {
      cbase[c * 8 + tid] = run;
      run += cs[c * 8 + tid];
    }
  }
}

// ---------------------------------------------------------------------------
// scatter: ballot-rank compact row assignment. One block per 32-token chunk.
// ---------------------------------------------------------------------------
__global__ __launch_bounds__(256) void scatter_kernel(const int* __restrict__ selE,
    const float* __restrict__ selG, const int* __restrict__ cbase,
    int* __restrict__ rowsel, int* __restrict__ tokrow, float* __restrict__ grow) {
  int chunk = blockIdx.x;
  int wave = threadIdx.x >> 6, lane = threadIdx.x & 63;
  int slot = chunk * 64 + lane;
  int sel = selE[slot];
  float g = selG[slot];
  int tokn = chunk * 32 + (lane >> 1);
  unsigned long long lt = (1ULL << lane) - 1ULL;
#pragma unroll
  for (int ei = 0; ei < 2; ei++) {
    int e = wave + ei * 4;
    unsigned long long m = __ballot(sel == e);
    if (sel == e) {
      int row = cbase[chunk * 8 + e] + __popcll(m & lt);
      rowsel[slot] = row;
      tokrow[row] = tokn;
      grow[row] = g;
    }
  }
}

// ---------------------------------------------------------------------------
// sparse grouped GEMM1 v2: gelu(gather(h_hi) @ w1t_e + b1_e) * g. K=1024.
// 64x64 tiles, dbuf, swizzle, XCD-grouped.
// ---------------------------------------------------------------------------
__global__ __launch_bounds__(256) void gexp1_kernel(const u16* __restrict__ A,
    const u16* __restrict__ w1t, const float* __restrict__ e_b1,
    const int* __restrict__ tokrow, const float* __restrict__ grow,
    const int* __restrict__ tileE2, const int* __restrict__ tileS2,
    const int* __restrict__ tileC2, const int* __restrict__ meta,
    u16* __restrict__ pb1) {
  __shared__ u16 As0[64 * 32];
  __shared__ u16 As1[64 * 32];
  __shared__ u16 Bs0[64 * 32];
  __shared__ u16 Bs1[64 * 32];
  __shared__ float gsl[64];
  int n = blockIdx.x;
  int ty = ((n >> 5) << 3) + (n & 7);
  int cblk = (n >> 3) & 3;
  if (ty >= meta[17]) return;
  int e = tileE2[ty], pstart = tileS2[ty], pcnt = tileC2[ty];
  int tid = threadIdx.x;
  int col0 = cblk * 64;
  if (tid < 64) {
    int rr = (tid < pcnt) ? tid : (pcnt - 1);
    gsl[tid] = grow[pstart + rr];
  }
  int wave = tid >> 6, lane = tid & 63;
  int wr = (wave >> 1) * 32, wc = (wave & 1) * 32;
  int l16 = lane & 15, qd = lane >> 4;
  int xq = qd ^ ((l16 >> 1) & 3);
  f32x4 acc[2][2];
  acc[0][0] = 0.0f; acc[0][1] = 0.0f; acc[1][0] = 0.0f; acc[1][1] = 0.0f;

  int r0 = tid >> 2, kc = tid & 3;
  int kcs = kc ^ ((r0 >> 1) & 3);
  int ra = (r0 < pcnt) ? r0 : (pcnt - 1);
  int ta = tokrow[pstart + ra];
  const u16* Ap = A + (size_t)ta * 1024 + kcs * 8;
  const u16* Bp = w1t + (size_t)(e * 256 + col0 + r0) * 1024 + kcs * 8;
  u16* dA0 = As0 + tid * 8;
  u16* dA1 = As1 + tid * 8;
  u16* dB0 = Bs0 + tid * 8;
  u16* dB1 = Bs1 + tid * 8;

  int aoff0 = (wr + l16) * 32 + xq * 8;
  int aoff1 = aoff0 + 16 * 32;
  int boff0 = (wc + l16) * 32 + xq * 8;
  int boff1 = boff0 + 16 * 32;

  gll16(Ap, dA0);
  gll16(Bp, dB0);
  __syncthreads();

  for (int k0 = 0; k0 < 1024; k0 += 64) {
    {
      gll16(Ap + k0 + 32, dA1);
      gll16(Bp + k0 + 32, dB1);
      bf16x8 a0 = *((const bf16x8*)(As0 + aoff0));
      bf16x8 a1 = *((const bf16x8*)(As0 + aoff1));
      bf16x8 b0 = *((const bf16x8*)(Bs0 + boff0));
      bf16x8 b1 = *((const bf16x8*)(Bs0 + boff1));
      acc[0][0] = __builtin_amdgcn_mfma_f32_16x16x32_bf16(a0, b0, acc[0][0], 0, 0, 0);
      acc[0][1] = __builtin_amdgcn_mfma_f32_16x16x32_bf16(a0, b1, acc[0][1], 0, 0, 0);
      acc[1][0] = __builtin_amdgcn_mfma_f32_16x16x32_bf16(a1, b0, acc[1][0], 0, 0, 0);
      acc[1][1] = __builtin_amdgcn_mfma_f32_16x16x32_bf16(a1, b1, acc[1][1], 0, 0, 0);
      __syncthreads();
    }
    {
      if (k0 + 64 < 1024) {
        gll16(Ap + k0 + 64, dA0);
        gll16(Bp + k0 + 64, dB0);
      }
      bf16x8 a0 = *((const bf16x8*)(As1 + aoff0));
      bf16x8 a1 = *((const bf16x8*)(As1 + aoff1));
      bf16x8 b0 = *((const bf16x8*)(Bs1 + boff0));
      bf16x8 b1 = *((const bf16x8*)(Bs1 + boff1));
      acc[0][0] = __builtin_amdgcn_mfma_f32_16x16x32_bf16(a0, b0, acc[0][0], 0, 0, 0);
      acc[0][1] = __builtin_amdgcn_mfma_f32_16x16x32_bf16(a0, b1, acc[0][1], 0, 0, 0);
      acc[1][0] = __builtin_amdgcn_mfma_f32_16x16x32_bf16(a1, b0, acc[1][0], 0, 0, 0);
      acc[1][1] = __builtin_amdgcn_mfma_f32_16x16x32_bf16(a1, b1, acc[1][1], 0, 0, 0);
      __syncthreads();
    }
  }

#pragma unroll
  for (int i = 0; i < 2; i++)
#pragma unroll
    for (int j = 0; j < 2; j++) {
      int cl = wc + j * 16 + l16;
      int col = col0 + cl;
      float bc = e_b1[e * 256 + col];
#pragma unroll
      for (int rr = 0; rr < 4; rr++) {
        int rl = wr + i * 16 + qd * 4 + rr;
        if (rl < pcnt) {
          float v = gelu_tanh(acc[i][j][rr] + bc) * gsl[rl];
          pb1[(size_t)(pstart + rl) * 256 + col] = f2bf(v);
        }
      }
    }
}

// ---------------------------------------------------------------------------
// sparse grouped GEMM2: pb1 @ w2te_e. K=256. dbuf, swizzle.
// ---------------------------------------------------------------------------
#define GX2_STAGE(K, AS, BS)              \
  gll16(Ap0 + (K), AS + tid * 8);         \
  gll16(Ap1 + (K), AS + tid * 8 + 2048);  \
  gll16(Bp0 + (K), BS + tid * 8);         \
  gll16(Bp1 + (K), BS + tid * 8 + 2048);

#define GX2_COMPUTE(AS, BS)                                                   \
  {                                                                           \
    bf16x8 af[4], bfr[4];                                                     \
    _Pragma("unroll") for (int i = 0; i < 4; i++) {                           \
      af[i]  = *((const bf16x8*)(AS + (wr + i * 16 + l16) * 32 + xq * 8));    \
      bfr[i] = *((const bf16x8*)(BS + (wc + i * 16 + l16) * 32 + xq * 8));    \
    }                                                                         \
    _Pragma("unroll") for (int i = 0; i < 4; i++)                             \
      _Pragma("unroll") for (int j = 0; j < 4; j++)                           \
        acc[i][j] = __builtin_amdgcn_mfma_f32_16x16x32_bf16(af[i], bfr[j], acc[i][j], 0, 0, 0); \
  }

__global__ __launch_bounds__(256) void gexp2_kernel(const u16* __restrict__ pb1,
    const u16* __restrict__ w2te,
    const int* __restrict__ tileE, const int* __restrict__ tileS,
    const int* __restrict__ tileC, const int* __restrict__ meta,
    u16* __restrict__ pb2) {
  int ty = blockIdx.y;
  if (ty >= meta[16]) return;
  int e = tileE[ty], pstart = tileS[ty], pcnt = tileC[ty];
  if (pcnt <= 0) return;
  __shared__ u16 As0[4096], As1[4096];
  __shared__ u16 Bs0[4096], Bs1[4096];
  int tid = threadIdx.x;
  int col0 = blockIdx.x * 128;
  int wave = tid >> 6, lane = tid & 63;
  int wr = (wave >> 1) * 64, wc = (wave & 1) * 64;
  int l16 = lane & 15, qd = lane >> 4;
  int xq = qd ^ ((l16 >> 1) & 3);
  f32x4 acc[4][4];
#pragma unroll
  for (int i = 0; i < 4; i++)
#pragma unroll
    for (int j = 0; j < 4; j++) acc[i][j] = 0.0f;

  int r0 = tid >> 2, kc = tid & 3;
  int kcs = kc ^ ((r0 >> 1) & 3);
  int ra = (r0 < pcnt) ? r0 : (pcnt - 1);
  int rb = (r0 + 64 < pcnt) ? (r0 + 64) : (pcnt - 1);
  const u16* Ap0 = pb1 + (size_t)(pstart + ra) * 256 + kcs * 8;
  const u16* Ap1 = pb1 + (size_t)(pstart + rb) * 256 + kcs * 8;
  const u16* Bp0 = w2te + (size_t)(e * 1024 + col0 + r0) * 256 + kcs * 8;
  const u16* Bp1 = Bp0 + (size_t)64 * 256;

  GX2_STAGE(0, As0, Bs0);
  __syncthreads();
  for (int k0 = 0; k0 < 256; k0 += 64) {
    GX2_STAGE(k0 + 32, As1, Bs1);
    GX2_COMPUTE(As0, Bs0);
    __syncthreads();
    if (k0 + 64 < 256) {
      GX2_STAGE(k0 + 64, As0, Bs0);
    }
    GX2_COMPUTE(As1, Bs1);
    __syncthreads();
  }

#pragma unroll
  for (int i = 0; i < 4; i++)
#pragma unroll
    for (int j = 0; j < 4; j++) {
      int cl = wc + j * 16 + l16;
#pragma unroll
      for (int rr = 0; rr < 4; rr++) {
        int rl = wr + i * 16 + qd * 4 + rr;
        if (rl < pcnt)
          pb2[(size_t)(pstart + rl) * 1024 + col0 + cl] = f2bf(acc[i][j][rr]);
      }
    }
}

// ---------------------------------------------------------------------------
// combine: stage = pairA + pairB + gA*b2[eA] + gB*b2[eB]; next = hidden+a*st.
// ---------------------------------------------------------------------------
__global__ __launch_bounds__(256) void combine_kernel(const u16* __restrict__ pb2,
    const int* __restrict__ rowsel, const int* __restrict__ selE,
    const float* __restrict__ selG, const float* __restrict__ e_b2,
    const float* __restrict__ hidden, const float* __restrict__ alpha_p,
    float* __restrict__ stage, float* __restrict__ next) {
  int t = blockIdx.x;
  int c = threadIdx.x * 4;
  int rA = rowsel[t * 2], rB = rowsel[t * 2 + 1];
  int eA = selE[t * 2], eB = selE[t * 2 + 1];
  float gA = selG[t * 2], gB = selG[t * 2 + 1];
  float al = alpha_p[0];
  ushort4 pa = *((const ushort4*)(pb2 + (size_t)rA * 1024 + c));
  ushort4 pb = *((const ushort4*)(pb2 + (size_t)rB * 1024 + c));
  float4 ba = *((const float4*)(e_b2 + (size_t)eA * 1024 + c));
  float4 bb = *((const float4*)(e_b2 + (size_t)eB * 1024 + c));
  float4 h = *((const float4*)(hidden + (size_t)t * 1024 + c));
  float4 v;
  v.x = b2f(pa.x) + b2f(pb.x) + gA * ba.x + gB * bb.x;
  v.y = b2f(pa.y) + b2f(pb.y) + gA * ba.y + gB * bb.y;
  v.z = b2f(pa.z) + b2f(pb.z) + gA * ba.z + gB * bb.z;
  v.w = b2f(pa.w) + b2f(pb.w) + gA * ba.w + gB * bb.w;
  *((float4*)(stage + (size_t)t * 1024 + c)) = v;
  float4 n;
  n.x = h.x + al * v.x; n.y = h.y + al * v.y;
  n.z = h.z + al * v.z; n.w = h.w + al * v.w;
  *((float4*)(next + (size_t)t * 1024 + c)) = n;
}

// ---------------------------------------------------------------------------
extern "C" void kernel_launch(void* const* d_in, const int* in_sizes, int n_in,
                              void* d_out, int out_size, void* d_ws, size_t ws_size,
                              hipStream_t stream) {
  const float* hidden    = (const float*)d_in[0];
  const float* feat      = (const float*)d_in[1];
  const float* feat_bank = (const float*)d_in[2];
  const float* ln_g  = (const float*)d_in[4];
  const float* ln_b  = (const float*)d_in[5];
  const float* fp_w1 = (const float*)d_in[6];
  const float* fp_b1 = (const float*)d_in[7];
  const float* fp_w2 = (const float*)d_in[8];
  const float* fp_b2 = (const float*)d_in[9];
  const float* r_w1  = (const float*)d_in[10];
  const float* r_b1  = (const float*)d_in[11];
  const float* r_w2  = (const float*)d_in[12];
  const float* r_b2  = (const float*)d_in[13];
  const float* rr_w  = (const float*)d_in[14];
  const float* rr_b  = (const float*)d_in[15];
  const float* e_w1  = (const float*)d_in[16];
  const float* e_b1  = (const float*)d_in[17];
  const float* e_w2  = (const float*)d_in[18];
  const float* e_b2  = (const float*)d_in[19];
  const float* alpha = (const float*)d_in[20];

  char* ob = (char*)d_out;
  float* next  = (float*)ob;
  float* stage = (float*)(ob + 33554432);
  float* gates = (float*)(ob + 67108864);
  float* slog  = gates + 65536;
  float* gw    = slog + 65536;
  float* rule  = gw + 32768;

  // next-region scratch (all dead before combine writes next)
  u16* fpw1t_hi = (u16*)(ob + 16777216);         // 256K [-> proj1]
  u16* fpw1t_lo = (u16*)(ob + 17039360);         // 256K
  float* wp     = (float*)(ob + 17301504);       // 256K [wprime -> tsplit]
  float* bp     = (float*)(ob + 17563648);       // 1K   [-> router]
  u16* rw1t_hi  = (u16*)(ob + 17825792);         // 640K [-> router]
  u16* rw1t_lo  = (u16*)(ob + 18481152);         // 640K
  u16* mid_hi   = (u16*)(ob + 19136512);         // 4M   [proj1 -> router]
  u16* mid_lo   = (u16*)(ob + 23330816);         // 4M
  u16* w2te     = (u16*)(ob + 19136512);         // 4M   [written AFTER router]

  // stage-region scratch (all dead before combine writes stage)
  char* sb = ob + 33554432;
  u16* pb1     = (u16*)sb;                       // 8M  [gexp1 -> gexp2]

  char* ws = (char*)d_ws;
  u16* h_hi = (u16*)(ws + WS_HHI);               // 16M
  u16* h_lo = (u16*)(ws + WS_HLO);               // 16M
  u16* pb2  = (u16*)(ws + WS_PB2);               // 32M
  u16* w1t  = (u16*)(ws + WS_W1T);               // 4M
  char* ix  = ws + WS_IDX;
  int*   selE   = (int*)(ix + IX_SELE);
  float* selG   = (float*)(ix + IX_SELG);
  int*   rowsel = (int*)(ix + IX_ROW);
  int*   tokrow = (int*)(ix + IX_TOKR);
  float* grow   = (float*)(ix + IX_GROW);
  int*   cnt    = (int*)(ix + IX_CNT);
  int*   cbase  = (int*)(ix + IX_CBASE);
  int*   tileE  = (int*)(ix + IX_TILEE);
  int*   tileS  = (int*)(ix + IX_TILES);
  int*   tileC  = (int*)(ix + IX_TILEC);
  int*   tileE2 = (int*)(ix + IX_TILEE2);
  int*   tileS2 = (int*)(ix + IX_TILES2);
  int*   tileC2 = (int*)(ix + IX_TILEC2);
  int*   meta   = (int*)(ix + IX_META);
  float* plog   = (float*)(ix + IX_PLOG);        // 1M [router -> gate]

  wprime_kernel<<<257, 256, 0, stream>>>(fp_w2, r_w1, fp_b2, r_b1, wp, bp);
  // transposed/split weights (coalesced LDS-tiled)
  tsplit_kernel<<<dim3(4, 8, 1), 256, 0, stream>>>(fp_w1, 512, 256,
      fpw1t_hi, fpw1t_lo, 512, 0);
  tsplit_kernel<<<dim3(4, 16, 1), 256, 0, stream>>>(r_w1, 1024, 256,
      rw1t_hi, rw1t_lo, 1280, 0);
  tsplit_kernel<<<dim3(4, 4, 1), 256, 0, stream>>>(wp, 256, 256,
      rw1t_hi, rw1t_lo, 1280, 1024);
  tsplit_kernel<<<dim3(4, 16, 8), 256, 0, stream>>>(e_w1, 1024, 256,
      w1t, nullptr, 1024, 0);
  ln_kernel<<<8192, 256, 0, stream>>>(hidden, ln_g, ln_b, feat, rr_w, rr_b,
                                      h_hi, h_lo, rule);
  // proj1 FUSED (+ bank split fused): mid = gelu(feat_bank @ fp_w1 + fp_b1)
  gfuse_bank_kernel<<<1024, 256, 0, stream>>>(
      feat_bank, fpw1t_hi, fpw1t_lo, fp_b1, mid_hi, mid_lo);
  // router FUSED (+ logit contraction fused): plog partials, K=1024+256
  gfuse_router_kernel<<<1024, 256, 0, stream>>>(
      h_hi, h_lo, mid_hi, mid_lo,
      rw1t_hi, rw1t_lo, bp, r_w2, plog);
  // e_w2 transpose into the now-dead mid region (after router gemm)
  tsplit_kernel<<<dim3(16, 4, 8), 256, 0, stream>>>(e_w2, 256, 1024,
      w2te, nullptr, 256, 0);
  gate_kernel<<<256, 256, 0, stream>>>(plog, r_b2, gates, slog, gw,
      selE, selG, cnt);
  stageb_kernel<<<1, 256, 0, stream>>>(cnt, cbase, tileE, tileS, tileC,
      tileE2, tileS2, tileC2, meta);
  scatter_kernel<<<256, 256, 0, stream>>>(selE, selG, cbase, rowsel, tokrow, grow);
  gexp1_kernel<<<1152, 256, 0, stream>>>(h_hi, w1t, e_b1, tokrow, grow,
      tileE2, tileS2, tileC2, meta, pb1);
  gexp2_kernel<<<dim3(8, 136), 256, 0, stream>>>(pb1, w2te, tileE, tileS, tileC,
      meta, pb2);
  combine_kernel<<<8192, 256, 0, stream>>>(pb2, rowsel, selE, selG, e_b2,
      hidden, alpha, stage, next);
}

// Round 8
// 335.151 us; speedup vs baseline: 1.0132x; 1.0132x over previous
//
#include <hip/hip_runtime.h>
#include <stdint.h>

// ---------------------------------------------------------------------------
// StageBranchRunnerN2 round 12:
//  - Model (r9/r10/r11 confirmed): stream is shared-HBM-BW bound; only byte
//    cuts move the wall (~0.2 us/MB). Biggest remaining flow: gexp2's A
//    re-fetch -- its dim3(8,136) grid round-robins the 8 col-blocks of one
//    tile across 8 XCDs, fetching the same pb1 slab 8x (~64 MB). Fix = the
//    r5 gexp1 recipe: 1-D XCD-grouped grid (1280 blocks), mapping
//    xcd=n&7, cblk=(n>>3)&7, ty=((n>>6)<<3)+(n&7) -> all 8 col-blocks of a
//    tile share an XCD; pb1 fetched once per tile.
//  - everything else unchanged from r11.
// ---------------------------------------------------------------------------

typedef unsigned short u16;
using bf16x8 = __attribute__((ext_vector_type(8))) short;
using f32x4  = __attribute__((ext_vector_type(4))) float;

// ws layout (ws >= 75,497,472 B)
#define WS_HHI 0u
#define WS_HLO 16777216u
#define WS_PB2 33554432u
#define WS_W1T 67108864u
#define WS_IDX 71303168u
// idx sub-offsets (bytes from ws+WS_IDX)
#define IX_SELE   0u        // int[16384]
#define IX_SELG   65536u    // float[16384]
#define IX_ROW    131072u   // int[16384]
#define IX_TOKR   196608u   // int[16384]
#define IX_GROW   262144u   // float[16384]
#define IX_CNT    327680u   // int[256*8]
#define IX_CBASE  335872u   // int[256*8]
#define IX_TILEE  344064u   // int[160]
#define IX_TILES  344704u   // int[160]
#define IX_TILEC  345344u   // int[160]
#define IX_META   345984u   // int[32]: [16]=nTiles128 [17]=nTiles64
#define IX_TILEE2 346112u   // int[288]
#define IX_TILES2 347264u   // int[288]
#define IX_TILEC2 348416u   // int[288]
#define IX_PLOG   1048576u  // float[8192][32] = 1 MB

__device__ __forceinline__ float gelu_tanh(float x) {
  float x3 = x * x * x;
  float t = tanhf(0.7978845608028654f * (x + 0.044715f * x3));
  return 0.5f * x * (1.0f + t);
}
__device__ __forceinline__ u16 f2bf(float f) {
  uint32_t u = __float_as_uint(f);
  u = u + 0x7fffu + ((u >> 16) & 1u);
  return (u16)(u >> 16);
}
__device__ __forceinline__ float b2f(u16 h) {
  return __uint_as_float(((uint32_t)h) << 16);
}
__device__ __forceinline__ void gll16(const void* g, void* l) {
  __builtin_amdgcn_global_load_lds(
      (const __attribute__((address_space(1))) void*)g,
      (__attribute__((address_space(3))) void*)l, 16, 0, 0);
}

// ---------------------------------------------------------------------------
// LDS-tiled transpose + bf16 split: in f32 [z][inR][inC] -> out bf16
// out[(z*inC + c)*outLD + outColOff + r]. 64x64 tile, coalesced both sides.
// ---------------------------------------------------------------------------
__global__ __launch_bounds__(256) void tsplit_kernel(const float* __restrict__ in,
    int inR, int inC, u16* __restrict__ outHi, u16* __restrict__ outLo,
    int outLD, int outColOff) {
  __shared__ u16 hs[64][65];
  __shared__ u16 ls[64][65];
  int tid = threadIdx.x;
  int c0 = blockIdx.x * 64, r0 = blockIdx.y * 64;
  const float* inp = in + (size_t)blockIdx.z * inR * inC;
  int rl = tid >> 6, cl = tid & 63;
#pragma unroll
  for (int p = 0; p < 16; p++) {
    int r = rl + p * 4;
    float v = inp[(size_t)(r0 + r) * inC + c0 + cl];
    u16 h = f2bf(v);
    hs[r][cl] = h;
    ls[r][cl] = f2bf(v - b2f(h));
  }
  __syncthreads();
  size_t obase = (size_t)(blockIdx.z * inC + c0) * outLD + outColOff + r0;
#pragma unroll
  for (int p = 0; p < 16; p++) {
    int c = rl + p * 4;
    outHi[obase + (size_t)c * outLD + cl] = hs[cl][c];
    if (outLo) outLo[obase + (size_t)c * outLD + cl] = ls[cl][c];
  }
}

// ---------------------------------------------------------------------------
// W' = fp_w2 @ r_w1[1024:1280,:], b' = r_b1 + fp_b2 @ r_w1[1024:]
// ---------------------------------------------------------------------------
__global__ __launch_bounds__(256) void wprime_kernel(const float* __restrict__ fp_w2,
    const float* __restrict__ r_w1, const float* __restrict__ fp_b2,
    const float* __restrict__ r_b1, float* __restrict__ wp, float* __restrict__ bp) {
  __shared__ float row[256];
  int i = blockIdx.x, n = threadIdx.x;
  if (i < 256) {
    row[n] = fp_w2[i * 256 + n];
    __syncthreads();
    float acc = 0.0f;
    for (int j = 0; j < 256; j++) acc += row[j] * r_w1[(size_t)(1024 + j) * 256 + n];
    wp[i * 256 + n] = acc;
  } else {
    row[n] = fp_b2[n];
    __syncthreads();
    float acc = r_b1[n];
    for (int j = 0; j < 256; j++) acc += row[j] * r_w1[(size_t)(1024 + j) * 256 + n];
    bp[n] = acc;
  }
}

// ---------------------------------------------------------------------------
// LayerNorm -> h hi/lo bf16 split; rule logits.
// ---------------------------------------------------------------------------
__global__ __launch_bounds__(256) void ln_kernel(const float* __restrict__ hidden,
    const float* __restrict__ ln_g, const float* __restrict__ ln_b,
    const float* __restrict__ feat, const float* __restrict__ rr_w,
    const float* __restrict__ rr_b,
    u16* __restrict__ h_hi, u16* __restrict__ h_lo, float* __restrict__ rule) {
  int t = blockIdx.x;
  int tid = threadIdx.x;
  float4 v = ((const float4*)(hidden + (size_t)t * 1024))[tid];
  float s = v.x + v.y + v.z + v.w;
#pragma unroll
  for (int o = 32; o > 0; o >>= 1) s += __shfl_down(s, o);
  __shared__ float red[4];
  __shared__ float stats[2];
  int wid = tid >> 6, lane = tid & 63;
  if (lane == 0) red[wid] = s;
  __syncthreads();
  if (tid == 0) stats[0] = (red[0] + red[1] + red[2] + red[3]) * (1.0f / 1024.0f);
  __syncthreads();
  float mu = stats[0];
  float dx = v.x - mu, dy = v.y - mu, dz = v.z - mu, dw = v.w - mu;
  float q = dx * dx + dy * dy + dz * dz + dw * dw;
#pragma unroll
  for (int o = 32; o > 0; o >>= 1) q += __shfl_down(q, o);
  if (lane == 0) red[wid] = q;
  __syncthreads();
  if (tid == 0) {
    float var = (red[0] + red[1] + red[2] + red[3]) * (1.0f / 1024.0f) + 1e-5f;
    float r = rsqrtf(var);
    r = r * (1.5f - 0.5f * var * r * r);
    stats[1] = r;
  }
  __syncthreads();
  float r = stats[1];
  float4 g = ((const float4*)ln_g)[tid];
  float4 b = ((const float4*)ln_b)[tid];
  float4 o;
  o.x = dx * r * g.x + b.x;
  o.y = dy * r * g.y + b.y;
  o.z = dz * r * g.z + b.z;
  o.w = dw * r * g.w + b.w;
  ushort4 hv, lv;
  hv.x = f2bf(o.x); lv.x = f2bf(o.x - b2f(hv.x));
  hv.y = f2bf(o.y); lv.y = f2bf(o.y - b2f(hv.y));
  hv.z = f2bf(o.z); lv.z = f2bf(o.z - b2f(hv.z));
  hv.w = f2bf(o.w); lv.w = f2bf(o.w - b2f(hv.w));
  ((ushort4*)(h_hi + (size_t)t * 1024))[tid] = hv;
  ((ushort4*)(h_lo + (size_t)t * 1024))[tid] = lv;
  if (tid < 8) {
    float acc = rr_b[tid];
#pragma unroll
    for (int f = 0; f < 16; f++) acc += feat[t * 16 + f] * rr_w[f * 8 + tid];
    rule[t * 8 + tid] = acc;
  }
}

// ---------------------------------------------------------------------------
// 32x64-tile fused GEMM compute: wave (wr in {0,16}, wc in {0,32}) owns a
// 16x32 sub-tile = 1 A-frag x 2 B-frags; 3-product split-bf16; 6 MFMA.
// ---------------------------------------------------------------------------
#define GF32_COMPUTE(AH, AL, BH, BL)                                           \
  {                                                                            \
    bf16x8 ah = *((const bf16x8*)(AH + (wr + l16) * 32 + xq * 8));             \
    bf16x8 al = *((const bf16x8*)(AL + (wr + l16) * 32 + xq * 8));             \
    _Pragma("unroll") for (int j = 0; j < 2; j++) {                            \
      bf16x8 bh = *((const bf16x8*)(BH + (wc + j * 16 + l16) * 32 + xq * 8));  \
      bf16x8 bl = *((const bf16x8*)(BL + (wc + j * 16 + l16) * 32 + xq * 8));  \
      acc[j] = __builtin_amdgcn_mfma_f32_16x16x32_bf16(ah, bh, acc[j], 0, 0, 0); \
      acc[j] = __builtin_amdgcn_mfma_f32_16x16x32_bf16(al, bh, acc[j], 0, 0, 0); \
      acc[j] = __builtin_amdgcn_mfma_f32_16x16x32_bf16(ah, bl, acc[j], 0, 0, 0); \
    }                                                                          \
  }

// ---------------------------------------------------------------------------
// proj1 FUSED + bank-split FUSED: mid = gelu(feat_bank @ fp_w1 + fp_b1).
// 32x64 tiles, 1024 blocks XCD-grouped. A reg-staged from f32 by threads
// 0-127 (float4 -> hi/lo bf16 -> swizzled ds_write); B via gll16.
// ---------------------------------------------------------------------------
__global__ __launch_bounds__(256) void gfuse_bank_kernel(
    const float* __restrict__ Af,            // [8192][512] f32
    const u16* __restrict__ Bth, const u16* __restrict__ Btl,  // [256][512]
    const float* __restrict__ bias,
    u16* __restrict__ outHi, u16* __restrict__ outLo) {
  __shared__ u16 Ash0[1024], Ash1[1024];
  __shared__ u16 Asl0[1024], Asl1[1024];
  __shared__ u16 Bsh0[2048], Bsh1[2048];
  __shared__ u16 Bsl0[2048], Bsl1[2048];
  int tid = threadIdx.x;
  int n = blockIdx.x;
  int rowt = ((n >> 5) << 3) + (n & 7);     // 0..255
  int cblk = (n >> 3) & 3;
  int row0 = rowt * 32, col0 = cblk * 64;
  int wave = tid >> 6, lane = tid & 63;
  int wr = (wave >> 1) * 16, wc = (wave & 1) * 32;
  int l16 = lane & 15, qd = lane >> 4;
  int xq = qd ^ ((l16 >> 1) & 3);
  f32x4 acc[2];
  acc[0] = 0.0f; acc[1] = 0.0f;

  int r0 = tid >> 2, kc = tid & 3;
  int ra = r0 & 31;                          // A row (threads 0-127)
  int kas8 = (kc ^ ((ra >> 1) & 3)) * 8;     // A swizzled k-slot (halves)
  int kbs8 = (kc ^ ((r0 >> 1) & 3)) * 8;     // B swizzled k-slot
  const float* Ap = Af + (size_t)(row0 + ra) * 512 + kc * 8;   // logical slot
  const u16* Bhp = Bth + (size_t)(col0 + r0) * 512 + kbs8;     // pre-swizzled
  const u16* Blp = Btl + (size_t)(col0 + r0) * 512 + kbs8;
  int aw = ra * 32 + kas8;                   // swizzled LDS write offset

  union U8 { ushort u[8]; bf16x8 v; };

#define GFB_STAGE(K, AH, AL, BH, BL)                                  \
  {                                                                   \
    gll16(Bhp + (K), BH + tid * 8);                                   \
    gll16(Blp + (K), BL + tid * 8);                                   \
    if (tid < 128) {                                                  \
      float4 va = *(const float4*)(Ap + (K));                         \
      float4 vb = *(const float4*)(Ap + (K) + 4);                     \
      float fv[8] = {va.x, va.y, va.z, va.w, vb.x, vb.y, vb.z, vb.w}; \
      U8 H, L;                                                        \
      _Pragma("unroll") for (int q = 0; q < 8; q++) {                 \
        H.u[q] = f2bf(fv[q]);                                         \
        L.u[q] = f2bf(fv[q] - b2f(H.u[q]));                           \
      }                                                               \
      *(bf16x8*)(AH + aw) = H.v;                                      \
      *(bf16x8*)(AL + aw) = L.v;                                      \
    }                                                                 \
  }

  GFB_STAGE(0, Ash0, Asl0, Bsh0, Bsl0);
  __syncthreads();
  for (int k0 = 0; k0 < 512; k0 += 64) {
    GFB_STAGE(k0 + 32, Ash1, Asl1, Bsh1, Bsl1);
    GF32_COMPUTE(Ash0, Asl0, Bsh0, Bsl0);
    __syncthreads();
    if (k0 + 64 < 512) {
      GFB_STAGE(k0 + 64, Ash0, Asl0, Bsh0, Bsl0);
    }
    GF32_COMPUTE(Ash1, Asl1, Bsh1, Bsl1);
    __syncthreads();
  }
#undef GFB_STAGE

#pragma unroll
  for (int j = 0; j < 2; j++) {
    int cl = wc + j * 16 + l16;
    float bc = bias[col0 + cl];
#pragma unroll
    for (int rr = 0; rr < 4; rr++) {
      int rl = wr + qd * 4 + rr;
      float v = gelu_tanh(acc[j][rr] + bc);
      u16 h = f2bf(v);
      size_t o = (size_t)(row0 + rl) * 256 + col0 + cl;
      outHi[o] = h;
      outLo[o] = f2bf(v - b2f(h));
    }
  }
}

// ---------------------------------------------------------------------------
// router FUSED, r1 never materialized: 32x64 tiles, 1024 blocks. Per-block
// r1 tile (32x64) contracted with r_w2[col0:+64, 0:8] -> plog partials.
// K = 1024 (h hi/lo) + 256 (mid hi/lo). A staged by threads 0-127.
// ---------------------------------------------------------------------------
__global__ __launch_bounds__(256) void gfuse_router_kernel(
    const u16* __restrict__ A1h, const u16* __restrict__ A1l,   // [8192][1024]
    const u16* __restrict__ A2h, const u16* __restrict__ A2l,   // [8192][256]
    const u16* __restrict__ Bth, const u16* __restrict__ Btl,   // [256][1280]
    const float* __restrict__ bias, const float* __restrict__ r_w2,
    float* __restrict__ plog) {
  __shared__ u16 Ash0[1024], Ash1[1024];
  __shared__ u16 Asl0[1024], Asl1[1024];
  __shared__ u16 Bsh0[2048], Bsh1[2048];
  __shared__ u16 Bsl0[2048], Bsl1[2048];
  __shared__ float r1s[32][65];
  __shared__ float w2s[64][8];
  int tid = threadIdx.x;
  int n = blockIdx.x;
  int rowt = ((n >> 5) << 3) + (n & 7);
  int cblk = (n >> 3) & 3;
  int row0 = rowt * 32, col0 = cblk * 64;
  int wave = tid >> 6, lane = tid & 63;
  int wr = (wave >> 1) * 16, wc = (wave & 1) * 32;
  int l16 = lane & 15, qd = lane >> 4;
  int xq = qd ^ ((l16 >> 1) & 3);
  f32x4 acc[2];
  acc[0] = 0.0f; acc[1] = 0.0f;

  int r0 = tid >> 2, kc = tid & 3;
  int ra = r0 & 31;
  int kas8 = (kc ^ ((ra >> 1) & 3)) * 8;
  int kbs8 = (kc ^ ((r0 >> 1) & 3)) * 8;
  const u16* A1hp = A1h + (size_t)(row0 + ra) * 1024 + kas8;
  const u16* A1lp = A1l + (size_t)(row0 + ra) * 1024 + kas8;
  const u16* A2hp = A2h + (size_t)(row0 + ra) * 256 + kas8;
  const u16* A2lp = A2l + (size_t)(row0 + ra) * 256 + kas8;
  const u16* Bhp = Bth + (size_t)(col0 + r0) * 1280 + kbs8;
  const u16* Blp = Btl + (size_t)(col0 + r0) * 1280 + kbs8;

#define GFR_STAGE(K, AH, AL, BH, BL)                      \
  {                                                       \
    int kk = (K);                                         \
    gll16(Bhp + kk, BH + tid * 8);                        \
    gll16(Blp + kk, BL + tid * 8);                        \
    if (tid < 128) {                                      \
      if (kk < 1024) {                                    \
        gll16(A1hp + kk, AH + tid * 8);                   \
        gll16(A1lp + kk, AL + tid * 8);                   \
      } else {                                            \
        gll16(A2hp + (kk - 1024), AH + tid * 8);          \
        gll16(A2lp + (kk - 1024), AL + tid * 8);          \
      }                                                   \
    }                                                     \
  }

  GFR_STAGE(0, Ash0, Asl0, Bsh0, Bsl0);
  __syncthreads();
  for (int k0 = 0; k0 < 1280; k0 += 64) {
    GFR_STAGE(k0 + 32, Ash1, Asl1, Bsh1, Bsl1);
    GF32_COMPUTE(Ash0, Asl0, Bsh0, Bsl0);
    __syncthreads();
    if (k0 + 64 < 1280) {
      GFR_STAGE(k0 + 64, Ash0, Asl0, Bsh0, Bsl0);
    }
    GF32_COMPUTE(Ash1, Asl1, Bsh1, Bsl1);
    __syncthreads();
  }
#undef GFR_STAGE

  // epilogue: r1 tile -> LDS, contract with w2 slice -> partial logits
#pragma unroll
  for (int j = 0; j < 2; j++) {
    int cl = wc + j * 16 + l16;
    float bc = bias[col0 + cl];
#pragma unroll
    for (int rr = 0; rr < 4; rr++) {
      int rl = wr + qd * 4 + rr;
      r1s[rl][cl] = gelu_tanh(acc[j][rr] + bc);
    }
  }
  for (int i = tid; i < 512; i += 256)
    w2s[i >> 3][i & 7] = r_w2[(size_t)(col0 + (i >> 3)) * 8 + (i & 7)];
  __syncthreads();
  {
    int tok = tid >> 3, e = tid & 7;       // 256 threads = 32 tok x 8 experts
    float L = 0.0f;
#pragma unroll
    for (int c = 0; c < 64; c++) L += r1s[tok][c] * w2s[c][e];
    plog[(size_t)(row0 + tok) * 32 + cblk * 8 + e] = L;
  }
}

// ---------------------------------------------------------------------------
// Gate: logits from plog partials, top-2 softmax, outputs, per-chunk counts.
// ---------------------------------------------------------------------------
__global__ __launch_bounds__(256) void gate_kernel(const float* __restrict__ plog,
    const float* __restrict__ r_b2,
    float* __restrict__ gates, float* __restrict__ slog, float* __restrict__ gw,
    int* __restrict__ selE, float* __restrict__ selG, int* __restrict__ cnt) {
  __shared__ float lg[32][8];
  __shared__ int se_s[64];
  int tid = threadIdx.x;
  int blk = blockIdx.x;
  int t0 = blk * 32;
  {
    int tl = tid >> 3, e = tid & 7;
    const float* pp = plog + (size_t)(t0 + tl) * 32 + e;
    lg[tl][e] = r_b2[e] + pp[0] + pp[8] + pp[16] + pp[24];
  }
  __syncthreads();
  if (tid < 32) {
    int t = t0 + tid;
    float l[8];
#pragma unroll
    for (int i = 0; i < 8; i++) l[i] = lg[tid][i];
    float m1 = -1e30f, m2 = -1e30f;
    int i1 = 0, i2 = 0;
#pragma unroll
    for (int i = 0; i < 8; i++) {
      float v = l[i];
      if (v > m1) { m2 = m1; i2 = i1; m1 = v; i1 = i; }
      else if (v > m2) { m2 = v; i2 = i; }
    }
    float w[8];
    float se = 0.0f;
#pragma unroll
    for (int i = 0; i < 8; i++) {
      float ex = (l[i] >= m2) ? expf(l[i] - m1) : 0.0f;
      w[i] = ex;
      se += ex;
    }
    float inv = 1.0f / se;
#pragma unroll
    for (int i = 0; i < 8; i++) {
      gates[(size_t)t * 8 + i] = w[i] * inv;
      slog[(size_t)t * 8 + i] = l[i];
    }
#pragma unroll
    for (int gi = 0; gi < 4; gi++)
      gw[(size_t)t * 4 + gi] = (w[2 * gi] + w[2 * gi + 1]) * inv;
    se_s[tid * 2] = i1;
    se_s[tid * 2 + 1] = i2;
    selE[t * 2] = i1;      selG[t * 2] = w[i1] * inv;
    selE[t * 2 + 1] = i2;  selG[t * 2 + 1] = w[i2] * inv;
  }
  __syncthreads();
  if (tid < 8) {
    int c = 0;
#pragma unroll
    for (int s = 0; s < 64; s++) c += (se_s[s] == tid) ? 1 : 0;
    cnt[blk * 8 + tid] = c;
  }
}

// ---------------------------------------------------------------------------
// stageB: expert totals -> bases -> per-chunk bases; tile maps (128 and 64).
// ---------------------------------------------------------------------------
__global__ __launch_bounds__(256) void stageb_kernel(const int* __restrict__ cnt,
    int* __restrict__ cbase, int* __restrict__ tileE, int* __restrict__ tileS,
    int* __restrict__ tileC, int* __restrict__ tileE2, int* __restrict__ tileS2,
    int* __restrict__ tileC2, int* __restrict__ meta) {
  __shared__ int cs[2048];
  __shared__ int tot[8];
  __shared__ int ebase[8];
  int tid = threadIdx.x;
  for (int i = tid; i < 2048; i += 256) cs[i] = cnt[i];
  __syncthreads();
  if (tid < 8) {
    int s = 0;
    for (int c = 0; c < 256; c++) s += cs[c * 8 + tid];
    tot[tid] = s;
  }
  __syncthreads();
  if (tid == 0) {
    int b = 0, nt = 0;
    for (int e = 0; e < 8; e++) {
      ebase[e] = b;
      int c = tot[e];
      for (int off = 0; off < c; off += 128) {
        tileE[nt] = e; tileS[nt] = b + off;
        tileC[nt] = (c - off < 128) ? (c - off) : 128;
        nt++;
      }
      b += c;
    }
    meta[16] = nt;
    int b2 = 0, nt2 = 0;
    for (int e = 0; e < 8; e++) {
      int c = tot[e];
      for (int off = 0; off < c; off += 64) {
        tileE2[nt2] = e; tileS2[nt2] = b2 + off;
        tileC2[nt2] = (c - off < 64) ? (c - off) : 64;
        nt2++;
      }
      b2 += c;
    }
    meta[17] = nt2;
  }
  __syncthreads();
  if (tid < 8) {
    int run = ebase[tid];
    for (int c = 0; c < 256; c++) {
      cbase[c * 8 + tid] = run;
      run += cs[c * 8 + tid];
    }
  }
}

// ---------------------------------------------------------------------------
// scatter: ballot-rank compact row assignment. One block per 32-token chunk.
// ---------------------------------------------------------------------------
__global__ __launch_bounds__(256) void scatter_kernel(const int* __restrict__ selE,
    const float* __restrict__ selG, const int* __restrict__ cbase,
    int* __restrict__ rowsel, int* __restrict__ tokrow, float* __restrict__ grow) {
  int chunk = blockIdx.x;
  int wave = threadIdx.x >> 6, lane = threadIdx.x & 63;
  int slot = chunk * 64 + lane;
  int sel = selE[slot];
  float g = selG[slot];
  int tokn = chunk * 32 + (lane >> 1);
  unsigned long long lt = (1ULL << lane) - 1ULL;
#pragma unroll
  for (int ei = 0; ei < 2; ei++) {
    int e = wave + ei * 4;
    unsigned long long m = __ballot(sel == e);
    if (sel == e) {
      int row = cbase[chunk * 8 + e] + __popcll(m & lt);
      rowsel[slot] = row;
      tokrow[row] = tokn;
      grow[row] = g;
    }
  }
}

// ---------------------------------------------------------------------------
// sparse grouped GEMM1 v2: gelu(gather(h_hi) @ w1t_e + b1_e) * g. K=1024.
// 64x64 tiles, dbuf, swizzle, XCD-grouped.
// ---------------------------------------------------------------------------
__global__ __launch_bounds__(256) void gexp1_kernel(const u16* __restrict__ A,
    const u16* __restrict__ w1t, const float* __restrict__ e_b1,
    const int* __restrict__ tokrow, const float* __restrict__ grow,
    const int* __restrict__ tileE2, const int* __restrict__ tileS2,
    const int* __restrict__ tileC2, const int* __restrict__ meta,
    u16* __restrict__ pb1) {
  __shared__ u16 As0[64 * 32];
  __shared__ u16 As1[64 * 32];
  __shared__ u16 Bs0[64 * 32];
  __shared__ u16 Bs1[64 * 32];
  __shared__ float gsl[64];
  int n = blockIdx.x;
  int ty = ((n >> 5) << 3) + (n & 7);
  int cblk = (n >> 3) & 3;
  if (ty >= meta[17]) return;
  int e = tileE2[ty], pstart = tileS2[ty], pcnt = tileC2[ty];
  int tid = threadIdx.x;
  int col0 = cblk * 64;
  if (tid < 64) {
    int rr = (tid < pcnt) ? tid : (pcnt - 1);
    gsl[tid] = grow[pstart + rr];
  }
  int wave = tid >> 6, lane = tid & 63;
  int wr = (wave >> 1) * 32, wc = (wave & 1) * 32;
  int l16 = lane & 15, qd = lane >> 4;
  int xq = qd ^ ((l16 >> 1) & 3);
  f32x4 acc[2][2];
  acc[0][0] = 0.0f; acc[0][1] = 0.0f; acc[1][0] = 0.0f; acc[1][1] = 0.0f;

  int r0 = tid >> 2, kc = tid & 3;
  int kcs = kc ^ ((r0 >> 1) & 3);
  int ra = (r0 < pcnt) ? r0 : (pcnt - 1);
  int ta = tokrow[pstart + ra];
  const u16* Ap = A + (size_t)ta * 1024 + kcs * 8;
  const u16* Bp = w1t + (size_t)(e * 256 + col0 + r0) * 1024 + kcs * 8;
  u16* dA0 = As0 + tid * 8;
  u16* dA1 = As1 + tid * 8;
  u16* dB0 = Bs0 + tid * 8;
  u16* dB1 = Bs1 + tid * 8;

  int aoff0 = (wr + l16) * 32 + xq * 8;
  int aoff1 = aoff0 + 16 * 32;
  int boff0 = (wc + l16) * 32 + xq * 8;
  int boff1 = boff0 + 16 * 32;

  gll16(Ap, dA0);
  gll16(Bp, dB0);
  __syncthreads();

  for (int k0 = 0; k0 < 1024; k0 += 64) {
    {
      gll16(Ap + k0 + 32, dA1);
      gll16(Bp + k0 + 32, dB1);
      bf16x8 a0 = *((const bf16x8*)(As0 + aoff0));
      bf16x8 a1 = *((const bf16x8*)(As0 + aoff1));
      bf16x8 b0 = *((const bf16x8*)(Bs0 + boff0));
      bf16x8 b1 = *((const bf16x8*)(Bs0 + boff1));
      acc[0][0] = __builtin_amdgcn_mfma_f32_16x16x32_bf16(a0, b0, acc[0][0], 0, 0, 0);
      acc[0][1] = __builtin_amdgcn_mfma_f32_16x16x32_bf16(a0, b1, acc[0][1], 0, 0, 0);
      acc[1][0] = __builtin_amdgcn_mfma_f32_16x16x32_bf16(a1, b0, acc[1][0], 0, 0, 0);
      acc[1][1] = __builtin_amdgcn_mfma_f32_16x16x32_bf16(a1, b1, acc[1][1], 0, 0, 0);
      __syncthreads();
    }
    {
      if (k0 + 64 < 1024) {
        gll16(Ap + k0 + 64, dA0);
        gll16(Bp + k0 + 64, dB0);
      }
      bf16x8 a0 = *((const bf16x8*)(As1 + aoff0));
      bf16x8 a1 = *((const bf16x8*)(As1 + aoff1));
      bf16x8 b0 = *((const bf16x8*)(Bs1 + boff0));
      bf16x8 b1 = *((const bf16x8*)(Bs1 + boff1));
      acc[0][0] = __builtin_amdgcn_mfma_f32_16x16x32_bf16(a0, b0, acc[0][0], 0, 0, 0);
      acc[0][1] = __builtin_amdgcn_mfma_f32_16x16x32_bf16(a0, b1, acc[0][1], 0, 0, 0);
      acc[1][0] = __builtin_amdgcn_mfma_f32_16x16x32_bf16(a1, b0, acc[1][0], 0, 0, 0);
      acc[1][1] = __builtin_amdgcn_mfma_f32_16x16x32_bf16(a1, b1, acc[1][1], 0, 0, 0);
      __syncthreads();
    }
  }

#pragma unroll
  for (int i = 0; i < 2; i++)
#pragma unroll
    for (int j = 0; j < 2; j++) {
      int cl = wc + j * 16 + l16;
      int col = col0 + cl;
      float bc = e_b1[e * 256 + col];
#pragma unroll
      for (int rr = 0; rr < 4; rr++) {
        int rl = wr + i * 16 + qd * 4 + rr;
        if (rl < pcnt) {
          float v = gelu_tanh(acc[i][j][rr] + bc) * gsl[rl];
          pb1[(size_t)(pstart + rl) * 256 + col] = f2bf(v);
        }
      }
    }
}

// ---------------------------------------------------------------------------
// sparse grouped GEMM2: pb1 @ w2te_e. K=256. dbuf, swizzle.
// round 12: XCD-grouped 1-D grid (1280 blocks) -- the 8 col-blocks of one
// tile share an XCD so the pb1 A-slab is fetched once, not 8x.
// ---------------------------------------------------------------------------
#define GX2_STAGE(K, AS, BS)              \
  gll16(Ap0 + (K), AS + tid * 8);         \
  gll16(Ap1 + (K), AS + tid * 8 + 2048);  \
  gll16(Bp0 + (K), BS + tid * 8);         \
  gll16(Bp1 + (K), BS + tid * 8 + 2048);

#define GX2_COMPUTE(AS, BS)                                                   \
  {                                                                           \
    bf16x8 af[4], bfr[4];                                                     \
    _Pragma("unroll") for (int i = 0; i < 4; i++) {                           \
      af[i]  = *((const bf16x8*)(AS + (wr + i * 16 + l16) * 32 + xq * 8));    \
      bfr[i] = *((const bf16x8*)(BS + (wc + i * 16 + l16) * 32 + xq * 8));    \
    }                                                                         \
    _Pragma("unroll") for (int i = 0; i < 4; i++)                             \
      _Pragma("unroll") for (int j = 0; j < 4; j++)                           \
        acc[i][j] = __builtin_amdgcn_mfma_f32_16x16x32_bf16(af[i], bfr[j], acc[i][j], 0, 0, 0); \
  }

__global__ __launch_bounds__(256) void gexp2_kernel(const u16* __restrict__ pb1,
    const u16* __restrict__ w2te,
    const int* __restrict__ tileE, const int* __restrict__ tileS,
    const int* __restrict__ tileC, const int* __restrict__ meta,
    u16* __restrict__ pb2) {
  // n -> xcd = n&7, cblk = (n>>3)&7, ty = ((n>>6)<<3) + (n&7).
  // For fixed ty, all 8 cblk values share n&7 -> same XCD -> A-slab L2 reuse.
  int n = blockIdx.x;
  int ty = ((n >> 6) << 3) + (n & 7);
  int cblk = (n >> 3) & 7;
  if (ty >= meta[16]) return;
  int e = tileE[ty], pstart = tileS[ty], pcnt = tileC[ty];
  if (pcnt <= 0) return;
  __shared__ u16 As0[4096], As1[4096];
  __shared__ u16 Bs0[4096], Bs1[4096];
  int tid = threadIdx.x;
  int col0 = cblk * 128;
  int wave = tid >> 6, lane = tid & 63;
  int wr = (wave >> 1) * 64, wc = (wave & 1) * 64;
  int l16 = lane & 15, qd = lane >> 4;
  int xq = qd ^ ((l16 >> 1) & 3);
  f32x4 acc[4][4];
#pragma unroll
  for (int i = 0; i < 4; i++)
#pragma unroll
    for (int j = 0; j < 4; j++) acc[i][j] = 0.0f;

  int r0 = tid >> 2, kc = tid & 3;
  int kcs = kc ^ ((r0 >> 1) & 3);
  int ra = (r0 < pcnt) ? r0 : (pcnt - 1);
  int rb = (r0 + 64 < pcnt) ? (r0 + 64) : (pcnt - 1);
  const u16* Ap0 = pb1 + (size_t)(pstart + ra) * 256 + kcs * 8;
  const u16* Ap1 = pb1 + (size_t)(pstart + rb) * 256 + kcs * 8;
  const u16* Bp0 = w2te + (size_t)(e * 1024 + col0 + r0) * 256 + kcs * 8;
  const u16* Bp1 = Bp0 + (size_t)64 * 256;

  GX2_STAGE(0, As0, Bs0);
  __syncthreads();
  for (int k0 = 0; k0 < 256; k0 += 64) {
    GX2_STAGE(k0 + 32, As1, Bs1);
    GX2_COMPUTE(As0, Bs0);
    __syncthreads();
    if (k0 + 64 < 256) {
      GX2_STAGE(k0 + 64, As0, Bs0);
    }
    GX2_COMPUTE(As1, Bs1);
    __syncthreads();
  }

#pragma unroll
  for (int i = 0; i < 4; i++)
#pragma unroll
    for (int j = 0; j < 4; j++) {
      int cl = wc + j * 16 + l16;
#pragma unroll
      for (int rr = 0; rr < 4; rr++) {
        int rl = wr + i * 16 + qd * 4 + rr;
        if (rl < pcnt)
          pb2[(size_t)(pstart + rl) * 1024 + col0 + cl] = f2bf(acc[i][j][rr]);
      }
    }
}

// ---------------------------------------------------------------------------
// combine: stage = pairA + pairB + gA*b2[eA] + gB*b2[eB]; next = hidden+a*st.
// ---------------------------------------------------------------------------
__global__ __launch_bounds__(256) void combine_kernel(const u16* __restrict__ pb2,
    const int* __restrict__ rowsel, const int* __restrict__ selE,
    const float* __restrict__ selG, const float* __restrict__ e_b2,
    const float* __restrict__ hidden, const float* __restrict__ alpha_p,
    float* __restrict__ stage, float* __restrict__ next) {
  int t = blockIdx.x;
  int c = threadIdx.x * 4;
  int rA = rowsel[t * 2], rB = rowsel[t * 2 + 1];
  int eA = selE[t * 2], eB = selE[t * 2 + 1];
  float gA = selG[t * 2], gB = selG[t * 2 + 1];
  float al = alpha_p[0];
  ushort4 pa = *((const ushort4*)(pb2 + (size_t)rA * 1024 + c));
  ushort4 pb = *((const ushort4*)(pb2 + (size_t)rB * 1024 + c));
  float4 ba = *((const float4*)(e_b2 + (size_t)eA * 1024 + c));
  float4 bb = *((const float4*)(e_b2 + (size_t)eB * 1024 + c));
  float4 h = *((const float4*)(hidden + (size_t)t * 1024 + c));
  float4 v;
  v.x = b2f(pa.x) + b2f(pb.x) + gA * ba.x + gB * bb.x;
  v.y = b2f(pa.y) + b2f(pb.y) + gA * ba.y + gB * bb.y;
  v.z = b2f(pa.z) + b2f(pb.z) + gA * ba.z + gB * bb.z;
  v.w = b2f(pa.w) + b2f(pb.w) + gA * ba.w + gB * bb.w;
  *((float4*)(stage + (size_t)t * 1024 + c)) = v;
  float4 n;
  n.x = h.x + al * v.x; n.y = h.y + al * v.y;
  n.z = h.z + al * v.z; n.w = h.w + al * v.w;
  *((float4*)(next + (size_t)t * 1024 + c)) = n;
}

// ---------------------------------------------------------------------------
extern "C" void kernel_launch(void* const* d_in, const int* in_sizes, int n_in,
                              void* d_out, int out_size, void* d_ws, size_t ws_size,
                              hipStream_t stream) {
  const float* hidden    = (const float*)d_in[0];
  const float* feat      = (const float*)d_in[1];
  const float* feat_bank = (const float*)d_in[2];
  const float* ln_g  = (const float*)d_in[4];
  const float* ln_b  = (const float*)d_in[5];
  const float* fp_w1 = (const float*)d_in[6];
  const float* fp_b1 = (const float*)d_in[7];
  const float* fp_w2 = (const float*)d_in[8];
  const float* fp_b2 = (const float*)d_in[9];
  const float* r_w1  = (const float*)d_in[10];
  const float* r_b1  = (const float*)d_in[11];
  const float* r_w2  = (const float*)d_in[12];
  const float* r_b2  = (const float*)d_in[13];
  const float* rr_w  = (const float*)d_in[14];
  const float* rr_b  = (const float*)d_in[15];
  const float* e_w1  = (const float*)d_in[16];
  const float* e_b1  = (const float*)d_in[17];
  const float* e_w2  = (const float*)d_in[18];
  const float* e_b2  = (const float*)d_in[19];
  const float* alpha = (const float*)d_in[20];

  char* ob = (char*)d_out;
  float* next  = (float*)ob;
  float* stage = (float*)(ob + 33554432);
  float* gates = (float*)(ob + 67108864);
  float* slog  = gates + 65536;
  float* gw    = slog + 65536;
  float* rule  = gw + 32768;

  // next-region scratch (all dead before combine writes next)
  u16* fpw1t_hi = (u16*)(ob + 16777216);         // 256K [-> proj1]
  u16* fpw1t_lo = (u16*)(ob + 17039360);         // 256K
  float* wp     = (float*)(ob + 17301504);       // 256K [wprime -> tsplit]
  float* bp     = (float*)(ob + 17563648);       // 1K   [-> router]
  u16* rw1t_hi  = (u16*)(ob + 17825792);         // 640K [-> router]
  u16* rw1t_lo  = (u16*)(ob + 18481152);         // 640K
  u16* mid_hi   = (u16*)(ob + 19136512);         // 4M   [proj1 -> router]
  u16* mid_lo   = (u16*)(ob + 23330816);         // 4M
  u16* w2te     = (u16*)(ob + 19136512);         // 4M   [written AFTER router]

  // stage-region scratch (all dead before combine writes stage)
  char* sb = ob + 33554432;
  u16* pb1     = (u16*)sb;                       // 8M  [gexp1 -> gexp2]

  char* ws = (char*)d_ws;
  u16* h_hi = (u16*)(ws + WS_HHI);               // 16M
  u16* h_lo = (u16*)(ws + WS_HLO);               // 16M
  u16* pb2  = (u16*)(ws + WS_PB2);               // 32M
  u16* w1t  = (u16*)(ws + WS_W1T);               // 4M
  char* ix  = ws + WS_IDX;
  int*   selE   = (int*)(ix + IX_SELE);
  float* selG   = (float*)(ix + IX_SELG);
  int*   rowsel = (int*)(ix + IX_ROW);
  int*   tokrow = (int*)(ix + IX_TOKR);
  float* grow   = (float*)(ix + IX_GROW);
  int*   cnt    = (int*)(ix + IX_CNT);
  int*   cbase  = (int*)(ix + IX_CBASE);
  int*   tileE  = (int*)(ix + IX_TILEE);
  int*   tileS  = (int*)(ix + IX_TILES);
  int*   tileC  = (int*)(ix + IX_TILEC);
  int*   tileE2 = (int*)(ix + IX_TILEE2);
  int*   tileS2 = (int*)(ix + IX_TILES2);
  int*   tileC2 = (int*)(ix + IX_TILEC2);
  int*   meta   = (int*)(ix + IX_META);
  float* plog   = (float*)(ix + IX_PLOG);        // 1M [router -> gate]

  wprime_kernel<<<257, 256, 0, stream>>>(fp_w2, r_w1, fp_b2, r_b1, wp, bp);
  // transposed/split weights (coalesced LDS-tiled)
  tsplit_kernel<<<dim3(4, 8, 1), 256, 0, stream>>>(fp_w1, 512, 256,
      fpw1t_hi, fpw1t_lo, 512, 0);
  tsplit_kernel<<<dim3(4, 16, 1), 256, 0, stream>>>(r_w1, 1024, 256,
      rw1t_hi, rw1t_lo, 1280, 0);
  tsplit_kernel<<<dim3(4, 4, 1), 256, 0, stream>>>(wp, 256, 256,
      rw1t_hi, rw1t_lo, 1280, 1024);
  tsplit_kernel<<<dim3(4, 16, 8), 256, 0, stream>>>(e_w1, 1024, 256,
      w1t, nullptr, 1024, 0);
  ln_kernel<<<8192, 256, 0, stream>>>(hidden, ln_g, ln_b, feat, rr_w, rr_b,
                                      h_hi, h_lo, rule);
  // proj1 FUSED (+ bank split fused): mid = gelu(feat_bank @ fp_w1 + fp_b1)
  gfuse_bank_kernel<<<1024, 256, 0, stream>>>(
      feat_bank, fpw1t_hi, fpw1t_lo, fp_b1, mid_hi, mid_lo);
  // router FUSED (+ logit contraction fused): plog partials, K=1024+256
  gfuse_router_kernel<<<1024, 256, 0, stream>>>(
      h_hi, h_lo, mid_hi, mid_lo,
      rw1t_hi, rw1t_lo, bp, r_w2, plog);
  // e_w2 transpose into the now-dead mid region (after router gemm)
  tsplit_kernel<<<dim3(16, 4, 8), 256, 0, stream>>>(e_w2, 256, 1024,
      w2te, nullptr, 256, 0);
  gate_kernel<<<256, 256, 0, stream>>>(plog, r_b2, gates, slog, gw,
      selE, selG, cnt);
  stageb_kernel<<<1, 256, 0, stream>>>(cnt, cbase, tileE, tileS, tileC,
      tileE2, tileS2, tileC2, meta);
  scatter_kernel<<<256, 256, 0, stream>>>(selE, selG, cbase, rowsel, tokrow, grow);
  gexp1_kernel<<<1152, 256, 0, stream>>>(h_hi, w1t, e_b1, tokrow, grow,
      tileE2, tileS2, tileC2, meta, pb1);
  gexp2_kernel<<<1280, 256, 0, stream>>>(pb1, w2te, tileE, tileS, tileC,
      meta, pb2);
  combine_kernel<<<8192, 256, 0, stream>>>(pb2, rowsel, selE, selG, e_b2,
      hidden, alpha, stage, next);
}